// Round 5
// baseline (294.792 us; speedup 1.0000x reference)
//
#include <hip/hip_runtime.h>
#include <hip/hip_bf16.h>
#include <cstdint>
#include <cstddef>

#define GS     128
#define OBS    1024
#define HSZ    256
#define OUTSZ  1024
#define NOUT   18
#define BATCH  256

typedef short  short8  __attribute__((ext_vector_type(8)));
typedef float  f32x4   __attribute__((ext_vector_type(4)));

__device__ __forceinline__ uint32_t f2bf_bits(float f) {
  uint32_t u = __builtin_bit_cast(uint32_t, f);
  return (u + 0x7fffu + ((u >> 16) & 1u)) >> 16;
}
__device__ __forceinline__ float bf_bits2f(uint32_t b) {
  return __builtin_bit_cast(float, b << 16);
}
__device__ __forceinline__ uint4 cvt8s(const float4 a, const float4 b) {
  float v[8] = {a.x, a.y, a.z, a.w, b.x, b.y, b.z, b.w};
  uint32_t h[8];
#pragma unroll
  for (int e = 0; e < 8; ++e) h[e] = f2bf_bits(v[e]);
  return make_uint4(h[0] | (h[1] << 16), h[2] | (h[3] << 16),
                    h[4] | (h[5] << 16), h[6] | (h[7] << 16));
}

// Raw barrier: ds ops drained, global loads stay in flight across it.
__device__ __forceinline__ void bar_lds() {
  asm volatile("s_waitcnt lgkmcnt(0)" ::: "memory");
  __builtin_amdgcn_s_barrier();
  __builtin_amdgcn_sched_barrier(0);
}

// ---------------------------------------------------------------------------
// P0 (merged preps):
//  blk <128   : W0cat [1024][512] -> WtP packed bf16:
//               element (k,col) at ((k>>5)*512 + col)*32 + (k&31)
//  blk 128-131: WlT[19][1024] (Wl^T rows 0..17, Wv row 18)
//  blk 132-163: W1bf[512][1024] bf16 of [W1_rel ; W1_root]
// ---------------------------------------------------------------------------
__global__ __launch_bounds__(256) void prep_kernel(
    const float* __restrict__ W0_rel, const float* __restrict__ W0_root,
    ushort* __restrict__ WtP, const float* __restrict__ Wl,
    const float* __restrict__ Wv, float* __restrict__ WlT,
    const float* __restrict__ W1_rel, const float* __restrict__ W1_root,
    ushort* __restrict__ W1bf)
{
  __shared__ float T[64][65];
  const int blk = blockIdx.x;
  const int t = threadIdx.x;
  if (blk < 128) {
    const int k0 = (blk & 15) * 64;
    const int n0 = (blk >> 4) * 64;
    for (int idx = t; idx < 4096; idx += 256) {
      const int r = idx >> 6, c = idx & 63;
      const int n = n0 + c;
      T[r][c] = (n < HSZ) ? W0_rel[(size_t)(k0 + r) * HSZ + n]
                          : W0_root[(size_t)(k0 + r) * HSZ + (n - HSZ)];
    }
    __syncthreads();
    for (int idx = t; idx < 512; idx += 256) {
      const int nl = idx >> 3;       // col-local 0..63
      const int kc = idx & 7;        // k-chunk, 8 k's each
      uint32_t h[8];
#pragma unroll
      for (int e = 0; e < 8; ++e) h[e] = f2bf_bits(T[kc * 8 + e][nl]);
      const int kg = k0 + kc * 8;
      const uint4 w = make_uint4(h[0] | (h[1] << 16), h[2] | (h[3] << 16),
                                 h[4] | (h[5] << 16), h[6] | (h[7] << 16));
      *(uint4*)&WtP[((size_t)((kg >> 5) * 512 + n0 + nl)) * 32 + (kg & 31)] = w;
    }
  } else if (blk < 132) {
    const int o = (blk - 128) * 256 + t;
#pragma unroll
    for (int c = 0; c < NOUT; ++c)
      WlT[(size_t)c * OUTSZ + o] = Wl[(size_t)o * NOUT + c];
    WlT[(size_t)18 * OUTSZ + o] = Wv[o];
  } else {
    const int base = (blk - 132) * 16384;
    for (int it = 0; it < 64; ++it) {
      const int idx = base + it * 256 + t;
      const int k = idx >> 10, o = idx & 1023;
      const float v = (k < HSZ) ? W1_rel[(size_t)k * OUTSZ + o]
                                : W1_root[(size_t)(k - HSZ) * OUTSZ + o];
      W1bf[idx] = (ushort)f2bf_bits(v);
    }
  }
}

// ---------------------------------------------------------------------------
// MEGA kernel: one block of 1024 threads (16 waves = 4 waves/SIMD) per sample.
//  A: adjacency masks (batched loads)
//  B: gemm0 Ys = bf16((x @ [W0_rel|W0_root])^T): BK=64 dbuf staging
//     (As2[2][128][72] overlaid on Ys), 16 raw barriers; wave owns 32
//     cat-cols (acc 64 f32); x prefetched 2 steps deep.
//  C: aggr P = A^T @ Yrel via MFMA; wave owns 16 h; relu + masked sum
//     -> a1s / rns
//  D: h1 = relu([a1|rn] @ W1bf + b1): 2 cols x 256 k per thread, halves
//     combined via LDS; logits/value via WlT
// ---------------------------------------------------------------------------
__global__ __launch_bounds__(1024, 4) void mega_kernel(
    const float* __restrict__ flat, const float* __restrict__ nodes,
    const int* __restrict__ num_nodes, const int* __restrict__ adj,
    const float* __restrict__ b0, const ushort* __restrict__ WtP,
    const ushort* __restrict__ W1bf, const float* __restrict__ b1,
    const float* __restrict__ WlT, const float* __restrict__ bl,
    const float* __restrict__ bv, float* __restrict__ out)
{
  __shared__ alignas(16) char smem[135168];            // Ys region, 132 KB
  ushort (*Ys)[264]     = (ushort (*)[264])smem;       // [256][264]
  ushort (*As2)[128][72] = (ushort (*)[128][72])smem;  // dbuf overlay, 36.9 KB
  float  (*part)[2]     = (float  (*)[2])smem;         // Phase D overlay, 4 KB
  __shared__ uint32_t rm[128][4];
  __shared__ uint32_t cmL[128][4];
  __shared__ float    a1s[256];
  __shared__ float    rns[256];
  __shared__ float    pl[19][8];

  const int b  = blockIdx.x;
  const int nb = num_nodes[b];
  const int t  = threadIdx.x;
  const int wv = t >> 6, lane = t & 63;
  const int ln = lane & 15, q = lane >> 4;

  // ---------------- Phase A: masks (batched loads, 8 rows/wave) ------------
  {
    const int* abase = adj + ((size_t)b * GS + wv * 8) * GS;
    int va[8], vb[8];
#pragma unroll
    for (int i = 0; i < 8; ++i) {
      va[i] = abase[i * GS + lane];
      vb[i] = abase[i * GS + 64 + lane];
    }
#pragma unroll
    for (int i = 0; i < 8; ++i) {
      const int k = wv * 8 + i;
      const unsigned long long m0 = __ballot(va[i] != 0);
      const unsigned long long m1 = __ballot(vb[i] != 0);
      if (lane == 0) {
        rm[k][0] = (uint32_t)m0; rm[k][1] = (uint32_t)(m0 >> 32);
        rm[k][2] = (uint32_t)m1; rm[k][3] = (uint32_t)(m1 >> 32);
      }
    }
  }
  __syncthreads();
  if (t < 128) {
    uint32_t c0 = 0, c1 = 0, c2 = 0, c3 = 0;
    const int w = t >> 5, sh = t & 31;
#pragma unroll 8
    for (int k = 0; k < 128; ++k) {
      const uint32_t bit = (rm[k][w] >> sh) & 1u;
      if (k < 32)      c0 |= bit << k;
      else if (k < 64) c1 |= bit << (k - 32);
      else if (k < 96) c2 |= bit << (k - 64);
      else             c3 |= bit << (k - 96);
    }
    cmL[t][0] = c0; cmL[t][1] = c1; cmL[t][2] = c2; cmL[t][3] = c3;
  }
  __syncthreads();
  if (t == 0) {
    cmL[nb][nb >> 5] |= 1u << (nb & 31);
    if (nb > 0) {
      cmL[nb - 1][nb >> 5] |= 1u << (nb & 31);
      cmL[nb][(nb - 1) >> 5] |= 1u << ((nb - 1) & 31);
    }
  }

  // ---------------- Phase B: gemm0 (BK=64, dbuf, 16 raw barriers) ----------
  const int arow = t >> 3;             // staging row 0..127
  const int akb  = (t & 7) * 8;        // 8 k's per thread within 64
  const float* xsrc = ((arow == nb) ? (flat + (size_t)b * OBS)
                                    : (nodes + ((size_t)b * GS + arow) * OBS)) + akb;
  // wave owns cat-cols [wv*32, +32); slice sl at +sl*16384
  const ushort* bptr = WtP + ((size_t)(wv * 32 + ln)) * 32 + q * 8;

  f32x4 acc[2][8] = {};   // [jj: col-tile][ii: node-tile], 64 f32

  { // stage step 0
    const float4 c0 = *(const float4*)(xsrc);
    const float4 c1 = *(const float4*)(xsrc + 4);
    *(uint4*)&As2[0][arow][akb] = cvt8s(c0, c1);
  }
  // x prefetch: steps 1 and 2 in flight
  float4 g0 = *(const float4*)(xsrc + 64);
  float4 g1 = *(const float4*)(xsrc + 68);
  float4 g2 = *(const float4*)(xsrc + 128);
  float4 g3 = *(const float4*)(xsrc + 132);
  bar_lds();

  for (int s = 0; s < 16; ++s) {
    const int buf = s & 1;
    const ushort* bpA = bptr + (size_t)(2 * s) * 16384;
    const short8 bA0 = *(const short8*)(bpA);
    const short8 bA1 = *(const short8*)(bpA + 512);
    const ushort* bpB = bptr + (size_t)(2 * s + 1) * 16384;
    const short8 bB0 = *(const short8*)(bpB);
    const short8 bB1 = *(const short8*)(bpB + 512);
#pragma unroll
    for (int ii = 0; ii < 8; ++ii) {
      const short8 ah = *(const short8*)&As2[buf][ii * 16 + ln][q * 8];
      acc[0][ii] = __builtin_amdgcn_mfma_f32_16x16x32_bf16(bA0, ah, acc[0][ii], 0, 0, 0);
      acc[1][ii] = __builtin_amdgcn_mfma_f32_16x16x32_bf16(bA1, ah, acc[1][ii], 0, 0, 0);
    }
    if (s + 1 < 16)
      *(uint4*)&As2[buf ^ 1][arow][akb] = cvt8s(g0, g1);
    g0 = g2; g1 = g3;
    if (s + 3 < 16) {
      g2 = *(const float4*)(xsrc + (s + 3) * 64);
      g3 = *(const float4*)(xsrc + (s + 3) * 64 + 4);
    }
#pragma unroll
    for (int ii = 0; ii < 8; ++ii) {
      const short8 ah2 = *(const short8*)&As2[buf][ii * 16 + ln][32 + q * 8];
      acc[0][ii] = __builtin_amdgcn_mfma_f32_16x16x32_bf16(bB0, ah2, acc[0][ii], 0, 0, 0);
      acc[1][ii] = __builtin_amdgcn_mfma_f32_16x16x32_bf16(bB1, ah2, acc[1][ii], 0, 0, 0);
    }
    bar_lds();
  }

  // epilogue -> Ys (As2 dead; Ys overlays it)
#pragma unroll
  for (int jj = 0; jj < 2; ++jj) {
    const int cat = wv * 32 + jj * 16 + q * 4;    // +r; side uniform per tile
    const int h   = cat & 255;
    const int kof = (cat < 256) ? 0 : 128;
#pragma unroll
    for (int ii = 0; ii < 8; ++ii) {
      const int kk = kof + ii * 16 + ln;
#pragma unroll
      for (int r = 0; r < 4; ++r)
        Ys[h + r][kk] = (ushort)f2bf_bits(acc[jj][ii][r]);
    }
  }
  __syncthreads();

  // ---------------- Phase C: aggregation (wave owns 16 h) ------------------
  f32x4 acc2[8] = {};
#pragma unroll
  for (int ks = 0; ks < 4; ++ks) {
    const short8 bf0 = *(const short8*)&Ys[wv * 16 + ln][ks * 32 + q * 8];
#pragma unroll
    for (int jt = 0; jt < 8; ++jt) {
      const uint32_t w = cmL[jt * 16 + ln][ks];
      const uint32_t byte_ = (w >> (q * 8)) & 0xFFu;
      short8 af;
#pragma unroll
      for (int i = 0; i < 8; ++i)
        af[i] = (short)(((byte_ >> i) & 1u) ? 0x3F80 : 0);
      acc2[jt] = __builtin_amdgcn_mfma_f32_16x16x32_bf16(af, bf0, acc2[jt], 0, 0, 0);
    }
  }

  const uint32_t S0 = cmL[nb][0], S1 = cmL[nb][1],
                 S2 = cmL[nb][2], S3 = cmL[nb][3];
  const int hl = wv * 16 + ln;
  const float bb0 = b0[hl];

  float asum0 = 0.f;
#pragma unroll
  for (int jt = 0; jt < 8; ++jt)
#pragma unroll
    for (int r = 0; r < 4; ++r) {
      const int j = jt * 16 + q * 4 + r;
      const uint32_t Sw = (j < 32) ? S0 : (j < 64) ? S1 : (j < 96) ? S2 : S3;
      const bool sj = (Sw >> (j & 31)) & 1u;
      const bool isn = (j == nb);
      const float yroot = bf_bits2f(Ys[hl][128 + j]);
      const float v = fmaxf(bb0 + yroot + acc2[jt][r], 0.f);
      if (sj) asum0 += v;
      if (isn) rns[hl] = v;
    }
  asum0 += __shfl_down(asum0, 32);
  asum0 += __shfl_down(asum0, 16);
  if (q == 0) a1s[hl] = asum0;
  __syncthreads();

  // ---------------- Phase D: gemm1 + head ----------------------------------
  const int oh = t >> 9;               // 0: a1 half (k 0..255), 1: rn half
  const int oc = t & 511;              // output col pair index
  const int o2 = oc * 2;
  float ax = 0.f, ay = 0.f;
  if (oh == 0) { ax = b1[o2]; ay = b1[o2 + 1]; }
  const ushort* wp = W1bf + (size_t)oh * 256 * OUTSZ + o2;
  const float* sv = oh ? rns : a1s;
#pragma unroll 8
  for (int k = 0; k < 256; ++k) {
    const ushort2 w2 = *(const ushort2*)(wp + (size_t)k * OUTSZ);
    const float s = sv[k];
    ax = fmaf(s, bf_bits2f(w2.x), ax);
    ay = fmaf(s, bf_bits2f(w2.y), ay);
  }
  if (oh == 1) { part[oc][0] = ax; part[oc][1] = ay; }  // Ys dead; overlay
  __syncthreads();
  if (oh == 0) {
    ax = fmaxf(ax + part[oc][0], 0.f);
    ay = fmaxf(ay + part[oc][1], 0.f);
    float p[19];
#pragma unroll
    for (int c = 0; c < 19; ++c) {
      const float2 w = *(const float2*)&WlT[(size_t)c * OUTSZ + o2];
      p[c] = ax * w.x + ay * w.y;
    }
#pragma unroll
    for (int c = 0; c < 19; ++c) {
      float v = p[c];
      v += __shfl_down(v, 32); v += __shfl_down(v, 16);
      v += __shfl_down(v, 8);  v += __shfl_down(v, 4);
      v += __shfl_down(v, 2);  v += __shfl_down(v, 1);
      if (lane == 0) pl[c][wv] = v;
    }
  }
  __syncthreads();
  if (t < 19) {
    float s = 0.f;
#pragma unroll
    for (int w = 0; w < 8; ++w) s += pl[t][w];
    if (t < NOUT) out[(size_t)b * NOUT + t] = s + bl[t];
    else          out[(size_t)BATCH * NOUT + b] = s + bv[0];
  }
}

// ---------------------------------------------------------------------------
extern "C" void kernel_launch(void* const* d_in, const int* in_sizes, int n_in,
                              void* d_out, int out_size, void* d_ws, size_t ws_size,
                              hipStream_t stream)
{
  const float* flat      = (const float*)d_in[0];
  const float* nodes     = (const float*)d_in[1];
  const int*   num_nodes = (const int*)  d_in[2];
  const int*   adj       = (const int*)  d_in[3];
  const float* W0_rel    = (const float*)d_in[5];
  const float* b0        = (const float*)d_in[6];
  const float* W0_root   = (const float*)d_in[7];
  const float* W1_rel    = (const float*)d_in[8];
  const float* b1        = (const float*)d_in[9];
  const float* W1_root   = (const float*)d_in[10];
  const float* Wl        = (const float*)d_in[11];
  const float* bl        = (const float*)d_in[12];
  const float* Wv        = (const float*)d_in[13];
  const float* bv        = (const float*)d_in[14];
  float* out = (float*)d_out;

  char* ws = (char*)d_ws;
  ushort* WtP  = (ushort*)ws;  ws += (size_t)512 * OBS * 2;   // 1 MiB
  float*  WlT  = (float*)ws;   ws += (size_t)19 * OUTSZ * 4;  // 76 KiB
  ushort* W1bf = (ushort*)ws;  ws += (size_t)512 * OUTSZ * 2; // 1 MiB

  prep_kernel<<<164, 256, 0, stream>>>(
      W0_rel, W0_root, WtP, Wl, Wv, WlT, W1_rel, W1_root, W1bf);
  mega_kernel<<<BATCH, 1024, 0, stream>>>(
      flat, nodes, num_nodes, adj, b0, WtP, W1bf, b1, WlT, bl, bv, out);
}